// Round 1
// baseline (293.588 us; speedup 1.0000x reference)
//
#include <hip/hip_runtime.h>
#include <cstdint>

// VQ-VAE vector quantizer, MI355X (gfx950).
// Round 0 design:
//  - scores s[n,k] = ||e_k||^2 - 2*z_n.e_k via f16 MFMA (16x16x32) with 2-term
//    hi/lo split on both operands (3 MFMAs: hh + lh + hl) -> ~fp32-exact argmin.
//  - emb scaled by 1024 before f16 conversion so lo-parts avoid f16 subnormals;
//    compare 1024*||e||^2 - 2*acc (same argmin).
//  - block = 128 threads (2 waves), BM=64 rows, grid=512 (2 blocks/CU).
//    A-fragments (z hi/lo) live in registers for the whole kernel (128 VGPRs);
//    inner loop reads only B-frags from LDS: 2 ds_read_b128 per 6 MFMAs.
//  - fused epilogue: gather emb[idx], write out, block-reduce loss, 1 atomicAdd.

typedef _Float16 f16;
typedef f16 f16x8 __attribute__((ext_vector_type(8)));
typedef f16 f16x4 __attribute__((ext_vector_type(4)));
typedef float f32x4 __attribute__((ext_vector_type(4)));

#define D_DIM 256
#define K_CODES 1024
#define BM 64                  // rows per block
#define BK 32                  // codes per LDS tile
#define NTILE (K_CODES / BK)   // 32
#define ESTRIDE (D_DIM + 8)    // 264 f16 = 528 B row stride: 16B-aligned, breaks
                               // the 32-bank power-of-2 conflict pattern

// Prep: zero the loss accumulator slot; compute ||e_k||^2 (unscaled fp32) into ws.
__global__ __launch_bounds__(256) void vq_prep(const float* __restrict__ emb,
                                               float* __restrict__ eTe,
                                               float* __restrict__ loss_slot) {
    if (blockIdx.x == 0 && threadIdx.x == 0) *loss_slot = 0.0f;
    if (!eTe) return;
    int gtid = blockIdx.x * 256 + threadIdx.x;
    int code = gtid >> 6;           // one wave per code
    int lane = threadIdx.x & 63;
    if (code >= K_CODES) return;
    float4 v = ((const float4*)(emb + (size_t)code * D_DIM))[lane];  // 64 lanes x 4 = 256
    float s = v.x * v.x + v.y * v.y + v.z * v.z + v.w * v.w;
    #pragma unroll
    for (int off = 32; off >= 1; off >>= 1) s += __shfl_down(s, off);
    if (lane == 0) eTe[code] = s;
}

__global__ __launch_bounds__(128, 1) void vq_main(const float* __restrict__ z,
                                                  const float* __restrict__ emb,
                                                  const float* __restrict__ eTe_g,
                                                  float* __restrict__ out,
                                                  float* __restrict__ loss_slot) {
    __shared__ __align__(16) f16 sEh[BK][ESTRIDE];   // 16896 B
    __shared__ __align__(16) f16 sEl[BK][ESTRIDE];   // 16896 B
    __shared__ float s_eTe[K_CODES];                 // 4096 B
    __shared__ int   s_idx[BM];                      // 256 B
    __shared__ float s_red[2];

    const int tid  = threadIdx.x;
    const int wave = tid >> 6;      // 0..1
    const int lane = tid & 63;
    const int m    = lane & 15;     // MFMA row (A) / col (B) index
    const int q    = lane >> 4;     // 0..3: k-group (frags) / row-group (C/D)
    const size_t row0 = (size_t)blockIdx.x * BM;

    // ||e||^2 into LDS (from ws, or per-block fallback if no workspace)
    if (eTe_g) {
        for (int i = tid; i < K_CODES; i += 128) s_eTe[i] = eTe_g[i];
    } else {
        for (int c = tid; c < K_CODES; c += 128) {
            const float4* r = (const float4*)(emb + (size_t)c * D_DIM);
            float s = 0.f;
            for (int j = 0; j < D_DIM / 4; j++) {
                float4 v = r[j];
                s += v.x * v.x + v.y * v.y + v.z * v.z + v.w * v.w;
            }
            s_eTe[c] = s;
        }
    }

    // A-fragments: z rows -> registers, f16 hi/lo split.
    // Wave w covers rows [32w, 32w+32): strips st=0,1 of 16 rows.
    // A layout (16x16x32): lane holds A[m = lane&15][k = q*8 + j], j=0..7.
    f16x8 Ah[2][8], Al[2][8];
    #pragma unroll
    for (int st = 0; st < 2; st++) {
        const size_t row = row0 + (size_t)wave * 32 + st * 16 + m;
        const float* zr = z + row * D_DIM;
        #pragma unroll
        for (int s = 0; s < 8; s++) {
            const float* p = zr + s * 32 + q * 8;
            float4 v0 = *(const float4*)p;
            float4 v1 = *(const float4*)(p + 4);
            float xs[8] = {v0.x, v0.y, v0.z, v0.w, v1.x, v1.y, v1.z, v1.w};
            f16x8 h, l;
            #pragma unroll
            for (int j = 0; j < 8; j++) {
                f16 hj = (f16)xs[j];
                h[j] = hj;
                l[j] = (f16)(xs[j] - (float)hj);
            }
            Ah[st][s] = h;
            Al[st][s] = l;
        }
    }

    float best[2][4];
    int   bidx[2][4];
    #pragma unroll
    for (int st = 0; st < 2; st++)
        #pragma unroll
        for (int r = 0; r < 4; r++) { best[st][r] = __builtin_inff(); bidx[st][r] = 0; }

    for (int t = 0; t < NTILE; t++) {
        __syncthreads();   // previous tile's reads done before overwrite
        // Stage E tile: BK codes x 256 dims, fp32 -> (x1024) f16 hi/lo in LDS.
        for (int i = tid; i < BK * (D_DIM / 4); i += 128) {
            int c  = i >> 6;          // code in tile (D_DIM/4 == 64)
            int dd = (i & 63) * 4;    // dim offset
            float4 v = *(const float4*)(emb + ((size_t)(t * BK + c)) * D_DIM + dd);
            float x0 = v.x * 1024.f, x1 = v.y * 1024.f, x2 = v.z * 1024.f, x3 = v.w * 1024.f;
            f16 h0 = (f16)x0, h1 = (f16)x1, h2 = (f16)x2, h3 = (f16)x3;
            f16x4 hv = {h0, h1, h2, h3};
            f16x4 lv = {(f16)(x0 - (float)h0), (f16)(x1 - (float)h1),
                        (f16)(x2 - (float)h2), (f16)(x3 - (float)h3)};
            *(f16x4*)&sEh[c][dd] = hv;
            *(f16x4*)&sEl[c][dd] = lv;
        }
        __syncthreads();

        #pragma unroll
        for (int ct = 0; ct < BK / 16; ct++) {
            f32x4 acc0 = {0.f, 0.f, 0.f, 0.f};
            f32x4 acc1 = {0.f, 0.f, 0.f, 0.f};
            #pragma unroll
            for (int s = 0; s < 8; s++) {
                // B layout: lane holds B[k = q*8+j][n = lane&15] = E[code m][k]
                f16x8 bh = *(const f16x8*)&sEh[ct * 16 + m][s * 32 + q * 8];
                f16x8 bl = *(const f16x8*)&sEl[ct * 16 + m][s * 32 + q * 8];
                acc0 = __builtin_amdgcn_mfma_f32_16x16x32_f16(Ah[0][s], bh, acc0, 0, 0, 0);
                acc1 = __builtin_amdgcn_mfma_f32_16x16x32_f16(Ah[1][s], bh, acc1, 0, 0, 0);
                acc0 = __builtin_amdgcn_mfma_f32_16x16x32_f16(Al[0][s], bh, acc0, 0, 0, 0);
                acc1 = __builtin_amdgcn_mfma_f32_16x16x32_f16(Al[1][s], bh, acc1, 0, 0, 0);
                acc0 = __builtin_amdgcn_mfma_f32_16x16x32_f16(Ah[0][s], bl, acc0, 0, 0, 0);
                acc1 = __builtin_amdgcn_mfma_f32_16x16x32_f16(Ah[1][s], bl, acc1, 0, 0, 0);
            }
            // C/D layout: acc[r] = S[row = q*4 + r][col = m]; code = tile base + m
            int code = t * BK + ct * 16 + m;
            float ete = 1024.f * s_eTe[code];   // scaled to match acc = z.(1024*e)
            #pragma unroll
            for (int r = 0; r < 4; r++) {
                float sc0 = ete - 2.f * acc0[r];
                if (sc0 < best[0][r]) { best[0][r] = sc0; bidx[0][r] = code; }
                float sc1 = ete - 2.f * acc1[r];
                if (sc1 < best[1][r]) { best[1][r] = sc1; bidx[1][r] = code; }
            }
        }
    }

    // Cross-lane argmin: reduce over the 16 column-lanes of each q-group.
    // First-index-wins tie-break matches np.argmin.
    #pragma unroll
    for (int st = 0; st < 2; st++) {
        #pragma unroll
        for (int r = 0; r < 4; r++) {
            float b  = best[st][r];
            int   bi = bidx[st][r];
            #pragma unroll
            for (int off = 8; off >= 1; off >>= 1) {
                float ob = __shfl_xor(b, off);
                int   oi = __shfl_xor(bi, off);
                if (ob < b || (ob == b && oi < bi)) { b = ob; bi = oi; }
            }
            if (m == 0) s_idx[wave * 32 + st * 16 + q * 4 + r] = bi;
        }
    }
    __syncthreads();

    // Fused epilogue: out = emb[idx] (== straight-through forward value),
    // loss partial = sum (e - z)^2.
    float lsum = 0.f;
    const size_t obase = row0 * D_DIM;
    for (int i = tid; i < BM * (D_DIM / 4); i += 128) {
        int r  = i >> 6;
        int dd = (i & 63) * 4;
        int idx = s_idx[r];
        float4 e  = *(const float4*)(emb + (size_t)idx * D_DIM + dd);
        size_t off = (size_t)r * D_DIM + dd;
        float4 zv = *(const float4*)(z + obase + off);
        *(float4*)(out + obase + off) = e;
        float d0 = e.x - zv.x, d1 = e.y - zv.y, d2 = e.z - zv.z, d3 = e.w - zv.w;
        lsum += d0 * d0 + d1 * d1 + d2 * d2 + d3 * d3;
    }
    #pragma unroll
    for (int off = 32; off >= 1; off >>= 1) lsum += __shfl_down(lsum, off);
    if (lane == 0) s_red[wave] = lsum;
    __syncthreads();
    if (tid == 0) {
        float total = s_red[0] + s_red[1];
        // loss = (1 + 0.25) * mean((q - z)^2); one device-scope atomic per block
        float scale = 1.25f / (float)((size_t)gridDim.x * BM * D_DIM);
        atomicAdd(loss_slot, total * scale);
    }
}

extern "C" void kernel_launch(void* const* d_in, const int* in_sizes, int n_in,
                              void* d_out, int out_size, void* d_ws, size_t ws_size,
                              hipStream_t stream) {
    const float* z   = (const float*)d_in[0];
    const float* emb = (const float*)d_in[1];
    float* out = (float*)d_out;
    const int N = in_sizes[0] / D_DIM;                 // 32768 rows
    float* loss_slot = out + (size_t)N * D_DIM;        // last element of d_out
    float* eTe = (ws_size >= K_CODES * sizeof(float)) ? (float*)d_ws : nullptr;

    vq_prep<<<K_CODES / 4, 256, 0, stream>>>(emb, eTe, loss_slot);
    vq_main<<<N / BM, 128, 0, stream>>>(z, emb, eTe, out, loss_slot);
}

// Round 2
// 247.634 us; speedup vs baseline: 1.1856x; 1.1856x over previous
//
#include <hip/hip_runtime.h>
#include <cstdint>

// VQ-VAE vector quantizer, MI355X (gfx950). Round 2.
//  - Single-term f16 MFMA (16x16x32): score = 1024*||e||^2 - 2*z.(1024e).
//    Index flips on near-ties are bounded (|e_a-e_b| <= 2/1024 ~ threshold-safe,
//    observed round-1 absmax 1.9e-3 passed) and loss impact ~1e-8.
//  - Codes processed as 8 resident LDS slices of 128 codes (64 KB f16),
//    fragment-linear layout: compute lane l reads chunk base+l -> zero bank
//    conflicts (round-1 layout was 8-way conflicted: 4.19M conflict cycles).
//  - 64 rows per wave (4 strips) -> 4 MFMAs + 4 independent acc chains per
//    ds_read_b128 -> MFMA-bound, latency hidden by ILP not occupancy.
//  - Epilogue: out = gather emb[idx] (L2-hot), loss from in-register f16 z
//    fragments -> z is read from HBM exactly once. HBM total ~64 MB.

typedef _Float16 f16;
typedef f16 f16x8 __attribute__((ext_vector_type(8)));
typedef float f32x4 __attribute__((ext_vector_type(4)));

#define D_DIM 256
#define K_CODES 1024
#define NSPLIT 8
#define CSPLIT (K_CODES / NSPLIT)   // 128 codes resident per slice
#define BM 128                      // rows per block (2 waves x 64 rows)
#define STRIPS 4                    // 16-row strips per wave

// Prep: zero the loss slot; ||e_k||^2 (fp32, unscaled) into ws.
__global__ __launch_bounds__(256) void vq_prep(const float* __restrict__ emb,
                                               float* __restrict__ eTe,
                                               float* __restrict__ loss_slot) {
    if (blockIdx.x == 0 && threadIdx.x == 0) *loss_slot = 0.0f;
    if (!eTe) return;
    int gtid = blockIdx.x * 256 + threadIdx.x;
    int code = gtid >> 6;           // one wave per code
    int lane = threadIdx.x & 63;
    if (code >= K_CODES) return;
    float4 v = ((const float4*)(emb + (size_t)code * D_DIM))[lane];
    float s = v.x * v.x + v.y * v.y + v.z * v.z + v.w * v.w;
    #pragma unroll
    for (int off = 32; off >= 1; off >>= 1) s += __shfl_down(s, off);
    if (lane == 0) eTe[code] = s;
}

__global__ __launch_bounds__(128) void vq_main(const float* __restrict__ z,
                                               const float* __restrict__ emb,
                                               const float* __restrict__ eTe_g,
                                               float* __restrict__ out,
                                               float* __restrict__ loss_slot,
                                               float loss_scale) {
    // Fragment-linear E slice: chunk index = ct*512 + s*64 + lane, 16 B each.
    __shared__ __align__(16) f16 sE[CSPLIT * D_DIM];   // 64 KB
    __shared__ float s_ete[CSPLIT];                    // pre-scaled by 1024
    __shared__ int   s_idx[BM];
    __shared__ float s_red[2];

    const int tid  = threadIdx.x;
    const int wave = tid >> 6;        // 0..1
    const int lane = tid & 63;
    const int m    = lane & 15;       // A row / B col / C col
    const int q    = lane >> 4;       // 0..3: k-group / C row-group
    const size_t row0 = (size_t)blockIdx.x * BM + (size_t)wave * 64;

    // ---- A fragments: 64 z rows -> f16, registers for the whole kernel ----
    // A layout: lane holds A[m][k = q*8 + j], k-block s covers dims s*32..+31.
    f16x8 A[STRIPS][8];
    #pragma unroll
    for (int st = 0; st < STRIPS; st++) {
        const float* zr = z + (row0 + st * 16 + m) * D_DIM;
        #pragma unroll
        for (int s = 0; s < 8; s++) {
            const float* p = zr + s * 32 + q * 8;
            float4 v0 = *(const float4*)p;
            float4 v1 = *(const float4*)(p + 4);
            f16x8 a = {(f16)v0.x, (f16)v0.y, (f16)v0.z, (f16)v0.w,
                       (f16)v1.x, (f16)v1.y, (f16)v1.z, (f16)v1.w};
            A[st][s] = a;
        }
    }

    float best[STRIPS][4];
    int   bidx[STRIPS][4];
    #pragma unroll
    for (int st = 0; st < STRIPS; st++)
        #pragma unroll
        for (int r = 0; r < 4; r++) { best[st][r] = __builtin_inff(); bidx[st][r] = 0; }

    const f16x8* sE8 = (const f16x8*)sE;

    #pragma unroll 1
    for (int sp = 0; sp < NSPLIT; sp++) {
        __syncthreads();   // previous slice fully consumed before overwrite

        // ||e||^2 for this slice (pre-scaled); tid indexes the 128 codes.
        if (eTe_g) {
            s_ete[tid] = 1024.0f * eTe_g[sp * CSPLIT + tid];
        } else {
            const float* p = emb + (size_t)(sp * CSPLIT + tid) * D_DIM;
            float ss = 0.f;
            for (int j = 0; j < D_DIM / 4; j++) {
                float4 v = ((const float4*)p)[j];
                ss += v.x * v.x + v.y * v.y + v.z * v.z + v.w * v.w;
            }
            s_ete[tid] = 1024.0f * ss;
        }

        // Stage slice: write chunks linearly (conflict-free), invert the
        // mapping to find the source dims: chunk ch -> code cc, dim-group g.
        const float* ebase = emb + (size_t)sp * CSPLIT * D_DIM;
        #pragma unroll 4
        for (int it = 0; it < 32; it++) {
            int ch = it * 128 + tid;
            int cc = ((ch >> 9) << 4) | (ch & 15);   // ct*16 + m
            int g  = (ch >> 4) & 31;                 // s*4 + q
            const float* p = ebase + cc * D_DIM + g * 8;
            float4 v0 = *(const float4*)p;
            float4 v1 = *(const float4*)(p + 4);
            f16x8 h = {(f16)(v0.x * 1024.f), (f16)(v0.y * 1024.f),
                       (f16)(v0.z * 1024.f), (f16)(v0.w * 1024.f),
                       (f16)(v1.x * 1024.f), (f16)(v1.y * 1024.f),
                       (f16)(v1.z * 1024.f), (f16)(v1.w * 1024.f)};
            *(f16x8*)(sE + (size_t)ch * 8) = h;
        }
        __syncthreads();

        // Compute: 8 code-subtiles x 8 k-steps; 1 ds_read_b128 feeds 4 MFMAs.
        for (int ct = 0; ct < 8; ct++) {
            f32x4 acc[STRIPS];
            #pragma unroll
            for (int st = 0; st < STRIPS; st++) acc[st] = (f32x4){0.f, 0.f, 0.f, 0.f};
            #pragma unroll
            for (int s = 0; s < 8; s++) {
                f16x8 bh = sE8[ct * 512 + s * 64 + lane];
                #pragma unroll
                for (int st = 0; st < STRIPS; st++)
                    acc[st] = __builtin_amdgcn_mfma_f32_16x16x32_f16(A[st][s], bh, acc[st], 0, 0, 0);
            }
            int codeL = ct * 16 + m;
            float ete = s_ete[codeL];          // broadcast within q-groups
            int code  = sp * CSPLIT + codeL;
            #pragma unroll
            for (int st = 0; st < STRIPS; st++)
                #pragma unroll
                for (int r = 0; r < 4; r++) {
                    float sc = fmaf(-2.0f, acc[st][r], ete);
                    if (sc < best[st][r]) { best[st][r] = sc; bidx[st][r] = code; }
                }
        }
    }

    // Cross-lane argmin over the 16 column-lanes; first-index tie-break.
    #pragma unroll
    for (int st = 0; st < STRIPS; st++)
        #pragma unroll
        for (int r = 0; r < 4; r++) {
            float b  = best[st][r];
            int   bi = bidx[st][r];
            #pragma unroll
            for (int off = 8; off >= 1; off >>= 1) {
                float ob = __shfl_xor(b, off);
                int   oi = __shfl_xor(bi, off);
                if (ob < b || (ob == b && oi < bi)) { b = ob; bi = oi; }
            }
            if (m == 0) s_idx[wave * 64 + st * 16 + q * 4 + r] = bi;
        }
    __syncthreads();

    // Epilogue: out = emb[idx] (fp32 gather, emb is L2-hot); loss from the
    // in-register f16 z fragments (no z re-read). Same scatter pattern as the
    // A load: 16 rows x 128 B contiguous per (st,s) across the wave.
    float lsum = 0.f;
    #pragma unroll
    for (int st = 0; st < STRIPS; st++) {
        int rl = wave * 64 + st * 16 + m;
        int idxv = s_idx[rl];
        const float* er = emb + (size_t)idxv * D_DIM;
        float* orow = out + ((size_t)blockIdx.x * BM + rl) * D_DIM;
        #pragma unroll
        for (int s = 0; s < 8; s++) {
            int dd = s * 32 + q * 8;
            float4 e0 = *(const float4*)(er + dd);
            float4 e1 = *(const float4*)(er + dd + 4);
            *(float4*)(orow + dd)     = e0;
            *(float4*)(orow + dd + 4) = e1;
            f16x8 a = A[st][s];
            float d0 = e0.x - (float)a[0], d1 = e0.y - (float)a[1];
            float d2 = e0.z - (float)a[2], d3 = e0.w - (float)a[3];
            float d4 = e1.x - (float)a[4], d5 = e1.y - (float)a[5];
            float d6 = e1.z - (float)a[6], d7 = e1.w - (float)a[7];
            lsum += d0*d0 + d1*d1 + d2*d2 + d3*d3 + d4*d4 + d5*d5 + d6*d6 + d7*d7;
        }
    }
    #pragma unroll
    for (int off = 32; off >= 1; off >>= 1) lsum += __shfl_down(lsum, off);
    if (lane == 0) s_red[wave] = lsum;
    __syncthreads();
    if (tid == 0) atomicAdd(loss_slot, (s_red[0] + s_red[1]) * loss_scale);
}

extern "C" void kernel_launch(void* const* d_in, const int* in_sizes, int n_in,
                              void* d_out, int out_size, void* d_ws, size_t ws_size,
                              hipStream_t stream) {
    const float* z   = (const float*)d_in[0];
    const float* emb = (const float*)d_in[1];
    float* out = (float*)d_out;
    const int NROWS = in_sizes[0] / D_DIM;              // 32768
    float* loss_slot = out + (size_t)in_sizes[0];       // last element of d_out
    float* eTe = (ws_size >= K_CODES * sizeof(float)) ? (float*)d_ws : nullptr;
    float loss_scale = 1.25f / (float)in_sizes[0];      // (1 + 0.25) * mean

    vq_prep<<<K_CODES / 4, 256, 0, stream>>>(emb, eTe, loss_slot);
    vq_main<<<NROWS / BM, 128, 0, stream>>>(z, emb, eTe, out, loss_slot, loss_scale);
}

// Round 3
// 138.262 us; speedup vs baseline: 2.1234x; 1.7910x over previous
//
#include <hip/hip_runtime.h>
#include <cstdint>

// VQ-VAE vector quantizer, MI355X (gfx950). Round 3.
// Fixes vs round 2 (evidence: VGPR_Count=256 + 15 MB scratch writes -> spills;
// 2-wave blocks -> 2 of 4 SIMDs idle, MFMA issue is per-SIMD):
//  - 4-wave blocks (256 thr), 32 rows/wave (STRIPS=2): A-frags 64 VGPRs,
//    __launch_bounds__(256,1) -> 512-reg budget, no spills, all SIMDs busy.
//  - prep converts emb -> f16 (x1024) into ws once; main stages slices with
//    async global_load_lds (16B) into double-buffered LDS (2 x 64 KB), issued
//    one slice ahead -> staging latency hidden behind MFMA compute.
//  - scoring math / fragment-linear LDS layout / fused epilogue unchanged
//    (verified passing in rounds 1-2).

typedef _Float16 f16;
typedef f16 f16x8 __attribute__((ext_vector_type(8)));
typedef float f32x4 __attribute__((ext_vector_type(4)));

#define D_DIM 256
#define K_CODES 1024
#define NSPLIT 8
#define CSPLIT (K_CODES / NSPLIT)   // 128 codes per LDS slice
#define BM 128                      // rows per block (4 waves x 32 rows)
#define STRIPS 2                    // 16-row strips per wave

__device__ __forceinline__ void async_copy16(const void* g, void* l) {
    __builtin_amdgcn_global_load_lds(
        (const __attribute__((address_space(1))) void*)g,
        (__attribute__((address_space(3))) void*)l, 16, 0, 0);
}

// ---- Prep: zero loss slot; emb -> f16 (x1024) row-major; eTe = 1024*||e||^2.
// grid 256 x 256 threads.
__global__ __launch_bounds__(256) void vq_prep(const float* __restrict__ emb,
                                               f16* __restrict__ emb16,
                                               float* __restrict__ eTe,
                                               float* __restrict__ loss_slot) {
    const int tid = threadIdx.x, wave = tid >> 6, lane = tid & 63;
    if (blockIdx.x == 0 && tid == 0) *loss_slot = 0.0f;

    // emb16: 32768 chunks of 8 dims; 128 chunks per block.
    if (tid < 128) {
        int ch = blockIdx.x * 128 + tid;
        int code = ch >> 5;
        int d8 = (ch & 31) * 8;
        const float* p = emb + (size_t)code * D_DIM + d8;
        float4 v0 = *(const float4*)p;
        float4 v1 = *(const float4*)(p + 4);
        f16x8 h = {(f16)(v0.x * 1024.f), (f16)(v0.y * 1024.f),
                   (f16)(v0.z * 1024.f), (f16)(v0.w * 1024.f),
                   (f16)(v1.x * 1024.f), (f16)(v1.y * 1024.f),
                   (f16)(v1.z * 1024.f), (f16)(v1.w * 1024.f)};
        *(f16x8*)(emb16 + (size_t)code * D_DIM + d8) = h;
    }

    // eTe: one wave per code, 4 codes per block.
    int code = blockIdx.x * 4 + wave;
    float4 v = ((const float4*)(emb + (size_t)code * D_DIM))[lane];
    float s = v.x * v.x + v.y * v.y + v.z * v.z + v.w * v.w;
    #pragma unroll
    for (int off = 32; off >= 1; off >>= 1) s += __shfl_down(s, off);
    if (lane == 0) eTe[code] = 1024.0f * s;
}

// ---- Main kernel -----------------------------------------------------------
__global__ __launch_bounds__(256, 1) void vq_main(const float* __restrict__ z,
                                                  const f16* __restrict__ emb16,
                                                  const float* __restrict__ eTe,
                                                  const float* __restrict__ emb,
                                                  float* __restrict__ out,
                                                  float* __restrict__ loss_slot,
                                                  float loss_scale) {
    // Double-buffered fragment-linear E slices. 2 x 64 KB.
    __shared__ __align__(16) f16 sE[2][CSPLIT * D_DIM];
    __shared__ int   s_idx[BM];
    __shared__ float s_red[4];

    const int tid  = threadIdx.x;
    const int wave = tid >> 6;        // 0..3
    const int lane = tid & 63;
    const int m    = lane & 15;       // A row / B col / C col
    const int q    = lane >> 4;       // 0..3: k-group / C row-group
    const size_t row0 = (size_t)blockIdx.x * BM + (size_t)wave * 32;

    // Stage slice 0 (async) before the A-load so both streams overlap.
    // Chunk ch = (ct*8 + s)*64 + l  ->  code ct*16 + (l&15), dim s*32 + (l>>4)*8.
    // Per wave: ch = ii*256 + wave*64 + lane -> LDS dest = base + lane*16. ✓
    {
        const f16* src = emb16;       // slice 0
        f16* dst = sE[0];
        #pragma unroll
        for (int ii = 0; ii < 16; ii++) {
            int ch = ii * 256 + wave * 64 + lane;
            int l  = ch & 63;
            int s  = (ch >> 6) & 7;
            int ct = ch >> 9;
            int code = ct * 16 + (l & 15);
            int dim  = s * 32 + (l >> 4) * 8;
            async_copy16(src + (size_t)code * D_DIM + dim, dst + (size_t)ch * 8);
        }
    }

    // A fragments: 32 z rows per wave -> f16 registers (64 VGPRs).
    // A layout: lane holds A[m][k = q*8 + j]; k-block s covers dims s*32..+31.
    f16x8 A[STRIPS][8];
    #pragma unroll
    for (int st = 0; st < STRIPS; st++) {
        const float* zr = z + (row0 + st * 16 + m) * D_DIM;
        #pragma unroll
        for (int s = 0; s < 8; s++) {
            const float* p = zr + s * 32 + q * 8;
            float4 v0 = *(const float4*)p;
            float4 v1 = *(const float4*)(p + 4);
            f16x8 a = {(f16)v0.x, (f16)v0.y, (f16)v0.z, (f16)v0.w,
                       (f16)v1.x, (f16)v1.y, (f16)v1.z, (f16)v1.w};
            A[st][s] = a;
        }
    }

    float best[STRIPS][4];
    int   bidx[STRIPS][4];
    #pragma unroll
    for (int st = 0; st < STRIPS; st++)
        #pragma unroll
        for (int r = 0; r < 4; r++) { best[st][r] = __builtin_inff(); bidx[st][r] = 0; }

    #pragma unroll 1
    for (int sp = 0; sp < NSPLIT; sp++) {
        // Barrier: drains this wave's outstanding global_load_lds (compiler
        // emits s_waitcnt vmcnt(0) before s_barrier) and syncs all waves ->
        // sE[sp&1] is fully staged; sE[(sp+1)&1] is no longer being read.
        __syncthreads();

        // Prefetch next slice (async) into the other buffer.
        if (sp + 1 < NSPLIT) {
            const f16* src = emb16 + (size_t)(sp + 1) * CSPLIT * D_DIM;
            f16* dst = sE[(sp + 1) & 1];
            #pragma unroll
            for (int ii = 0; ii < 16; ii++) {
                int ch = ii * 256 + wave * 64 + lane;
                int l  = ch & 63;
                int s  = (ch >> 6) & 7;
                int ct = ch >> 9;
                int code = ct * 16 + (l & 15);
                int dim  = s * 32 + (l >> 4) * 8;
                async_copy16(src + (size_t)code * D_DIM + dim, dst + (size_t)ch * 8);
            }
        }

        // Compute on current slice: 8 subtiles x 8 k-steps;
        // 1 ds_read_b128 feeds 2 MFMAs (2 row-strips).
        const f16x8* B8 = (const f16x8*)sE[sp & 1];
        for (int ct = 0; ct < 8; ct++) {
            f32x4 a0 = {0.f, 0.f, 0.f, 0.f};
            f32x4 a1 = {0.f, 0.f, 0.f, 0.f};
            #pragma unroll
            for (int s = 0; s < 8; s++) {
                f16x8 b = B8[ct * 512 + s * 64 + lane];
                a0 = __builtin_amdgcn_mfma_f32_16x16x32_f16(A[0][s], b, a0, 0, 0, 0);
                a1 = __builtin_amdgcn_mfma_f32_16x16x32_f16(A[1][s], b, a1, 0, 0, 0);
            }
            int code = sp * CSPLIT + ct * 16 + m;
            float ete = eTe[code];               // L1-hot global read
            #pragma unroll
            for (int r = 0; r < 4; r++) {
                float sc0 = fmaf(-2.0f, a0[r], ete);
                if (sc0 < best[0][r]) { best[0][r] = sc0; bidx[0][r] = code; }
                float sc1 = fmaf(-2.0f, a1[r], ete);
                if (sc1 < best[1][r]) { best[1][r] = sc1; bidx[1][r] = code; }
            }
        }
    }

    // Cross-lane argmin over the 16 column-lanes; first-index tie-break.
    #pragma unroll
    for (int st = 0; st < STRIPS; st++)
        #pragma unroll
        for (int r = 0; r < 4; r++) {
            float b  = best[st][r];
            int   bi = bidx[st][r];
            #pragma unroll
            for (int off = 8; off >= 1; off >>= 1) {
                float ob = __shfl_xor(b, off);
                int   oi = __shfl_xor(bi, off);
                if (ob < b || (ob == b && oi < bi)) { b = ob; bi = oi; }
            }
            if (m == 0) s_idx[wave * 32 + st * 16 + q * 4 + r] = bi;
        }
    __syncthreads();

    // Fused epilogue: out = emb[idx] (fp32, L2-hot); loss from in-register
    // f16 z fragments (z read from HBM exactly once).
    float lsum = 0.f;
    #pragma unroll
    for (int st = 0; st < STRIPS; st++) {
        int rl = wave * 32 + st * 16 + m;
        int idxv = s_idx[rl];
        const float* er = emb + (size_t)idxv * D_DIM;
        float* orow = out + ((size_t)blockIdx.x * BM + rl) * D_DIM;
        #pragma unroll
        for (int s = 0; s < 8; s++) {
            int dd = s * 32 + q * 8;
            float4 e0 = *(const float4*)(er + dd);
            float4 e1 = *(const float4*)(er + dd + 4);
            *(float4*)(orow + dd)     = e0;
            *(float4*)(orow + dd + 4) = e1;
            f16x8 a = A[st][s];
            float d0 = e0.x - (float)a[0], d1 = e0.y - (float)a[1];
            float d2 = e0.z - (float)a[2], d3 = e0.w - (float)a[3];
            float d4 = e1.x - (float)a[4], d5 = e1.y - (float)a[5];
            float d6 = e1.z - (float)a[6], d7 = e1.w - (float)a[7];
            lsum += d0*d0 + d1*d1 + d2*d2 + d3*d3 + d4*d4 + d5*d5 + d6*d6 + d7*d7;
        }
    }
    #pragma unroll
    for (int off = 32; off >= 1; off >>= 1) lsum += __shfl_down(lsum, off);
    if (lane == 0) s_red[wave] = lsum;
    __syncthreads();
    if (tid == 0)
        atomicAdd(loss_slot, (s_red[0] + s_red[1] + s_red[2] + s_red[3]) * loss_scale);
}

// ---- Fallback (round-2 kernels, verified passing) — used only if ws_size
// cannot hold emb16 + eTe. -----------------------------------------------
__global__ __launch_bounds__(256) void vq_prep_fb(const float* __restrict__ emb,
                                                  float* __restrict__ eTe,
                                                  float* __restrict__ loss_slot) {
    if (blockIdx.x == 0 && threadIdx.x == 0) *loss_slot = 0.0f;
    if (!eTe) return;
    int gtid = blockIdx.x * 256 + threadIdx.x;
    int code = gtid >> 6;
    int lane = threadIdx.x & 63;
    if (code >= K_CODES) return;
    float4 v = ((const float4*)(emb + (size_t)code * D_DIM))[lane];
    float s = v.x * v.x + v.y * v.y + v.z * v.z + v.w * v.w;
    #pragma unroll
    for (int off = 32; off >= 1; off >>= 1) s += __shfl_down(s, off);
    if (lane == 0) eTe[code] = s;
}

__global__ __launch_bounds__(128) void vq_main_fb(const float* __restrict__ z,
                                                  const float* __restrict__ emb,
                                                  const float* __restrict__ eTe_g,
                                                  float* __restrict__ out,
                                                  float* __restrict__ loss_slot,
                                                  float loss_scale) {
    __shared__ __align__(16) f16 sE[CSPLIT * D_DIM];
    __shared__ float s_ete[CSPLIT];
    __shared__ int   s_idx2[128];
    __shared__ float s_red2[2];

    const int tid  = threadIdx.x;
    const int wave = tid >> 6;
    const int lane = tid & 63;
    const int m    = lane & 15;
    const int q    = lane >> 4;
    const size_t row0 = (size_t)blockIdx.x * 128 + (size_t)wave * 64;

    f16x8 A[4][8];
    #pragma unroll
    for (int st = 0; st < 4; st++) {
        const float* zr = z + (row0 + st * 16 + m) * D_DIM;
        #pragma unroll
        for (int s = 0; s < 8; s++) {
            const float* p = zr + s * 32 + q * 8;
            float4 v0 = *(const float4*)p;
            float4 v1 = *(const float4*)(p + 4);
            f16x8 a = {(f16)v0.x, (f16)v0.y, (f16)v0.z, (f16)v0.w,
                       (f16)v1.x, (f16)v1.y, (f16)v1.z, (f16)v1.w};
            A[st][s] = a;
        }
    }
    float best[4][4]; int bidx[4][4];
    #pragma unroll
    for (int st = 0; st < 4; st++)
        #pragma unroll
        for (int r = 0; r < 4; r++) { best[st][r] = __builtin_inff(); bidx[st][r] = 0; }

    const f16x8* sE8 = (const f16x8*)sE;
    #pragma unroll 1
    for (int sp = 0; sp < NSPLIT; sp++) {
        __syncthreads();
        if (eTe_g) s_ete[tid] = 1024.0f * eTe_g[sp * CSPLIT + tid];
        else {
            const float* p = emb + (size_t)(sp * CSPLIT + tid) * D_DIM;
            float ss = 0.f;
            for (int j = 0; j < D_DIM / 4; j++) {
                float4 v = ((const float4*)p)[j];
                ss += v.x * v.x + v.y * v.y + v.z * v.z + v.w * v.w;
            }
            s_ete[tid] = 1024.0f * ss;
        }
        const float* ebase = emb + (size_t)sp * CSPLIT * D_DIM;
        #pragma unroll 4
        for (int it = 0; it < 32; it++) {
            int ch = it * 128 + tid;
            int cc = ((ch >> 9) << 4) | (ch & 15);
            int g  = (ch >> 4) & 31;
            const float* p = ebase + cc * D_DIM + g * 8;
            float4 v0 = *(const float4*)p;
            float4 v1 = *(const float4*)(p + 4);
            f16x8 h = {(f16)(v0.x * 1024.f), (f16)(v0.y * 1024.f),
                       (f16)(v0.z * 1024.f), (f16)(v0.w * 1024.f),
                       (f16)(v1.x * 1024.f), (f16)(v1.y * 1024.f),
                       (f16)(v1.z * 1024.f), (f16)(v1.w * 1024.f)};
            *(f16x8*)(sE + (size_t)ch * 8) = h;
        }
        __syncthreads();
        for (int ct = 0; ct < 8; ct++) {
            f32x4 acc[4];
            #pragma unroll
            for (int st = 0; st < 4; st++) acc[st] = (f32x4){0.f, 0.f, 0.f, 0.f};
            #pragma unroll
            for (int s = 0; s < 8; s++) {
                f16x8 bh = sE8[ct * 512 + s * 64 + lane];
                #pragma unroll
                for (int st = 0; st < 4; st++)
                    acc[st] = __builtin_amdgcn_mfma_f32_16x16x32_f16(A[st][s], bh, acc[st], 0, 0, 0);
            }
            int codeL = ct * 16 + m;
            float ete = s_ete[codeL];
            int code  = sp * CSPLIT + codeL;
            #pragma unroll
            for (int st = 0; st < 4; st++)
                #pragma unroll
                for (int r = 0; r < 4; r++) {
                    float sc = fmaf(-2.0f, acc[st][r], ete);
                    if (sc < best[st][r]) { best[st][r] = sc; bidx[st][r] = code; }
                }
        }
    }
    #pragma unroll
    for (int st = 0; st < 4; st++)
        #pragma unroll
        for (int r = 0; r < 4; r++) {
            float b = best[st][r]; int bi = bidx[st][r];
            #pragma unroll
            for (int off = 8; off >= 1; off >>= 1) {
                float ob = __shfl_xor(b, off);
                int   oi = __shfl_xor(bi, off);
                if (ob < b || (ob == b && oi < bi)) { b = ob; bi = oi; }
            }
            if (m == 0) s_idx2[wave * 64 + st * 16 + q * 4 + r] = bi;
        }
    __syncthreads();
    float lsum = 0.f;
    #pragma unroll
    for (int st = 0; st < 4; st++) {
        int rl = wave * 64 + st * 16 + m;
        int idxv = s_idx2[rl];
        const float* er = emb + (size_t)idxv * D_DIM;
        float* orow = out + ((size_t)blockIdx.x * 128 + rl) * D_DIM;
        #pragma unroll
        for (int s = 0; s < 8; s++) {
            int dd = s * 32 + q * 8;
            float4 e0 = *(const float4*)(er + dd);
            float4 e1 = *(const float4*)(er + dd + 4);
            *(float4*)(orow + dd)     = e0;
            *(float4*)(orow + dd + 4) = e1;
            f16x8 a = A[st][s];
            float d0 = e0.x - (float)a[0], d1 = e0.y - (float)a[1];
            float d2 = e0.z - (float)a[2], d3 = e0.w - (float)a[3];
            float d4 = e1.x - (float)a[4], d5 = e1.y - (float)a[5];
            float d6 = e1.z - (float)a[6], d7 = e1.w - (float)a[7];
            lsum += d0*d0 + d1*d1 + d2*d2 + d3*d3 + d4*d4 + d5*d5 + d6*d6 + d7*d7;
        }
    }
    #pragma unroll
    for (int off = 32; off >= 1; off >>= 1) lsum += __shfl_down(lsum, off);
    if (lane == 0) s_red2[wave] = lsum;
    __syncthreads();
    if (tid == 0) atomicAdd(loss_slot, (s_red2[0] + s_red2[1]) * loss_scale);
}

extern "C" void kernel_launch(void* const* d_in, const int* in_sizes, int n_in,
                              void* d_out, int out_size, void* d_ws, size_t ws_size,
                              hipStream_t stream) {
    const float* z   = (const float*)d_in[0];
    const float* emb = (const float*)d_in[1];
    float* out = (float*)d_out;
    const int NROWS = in_sizes[0] / D_DIM;              // 32768
    float* loss_slot = out + (size_t)in_sizes[0];
    float loss_scale = 1.25f / (float)in_sizes[0];

    const size_t emb16_bytes = (size_t)K_CODES * D_DIM * sizeof(f16);  // 512 KB
    const size_t need = emb16_bytes + K_CODES * sizeof(float);

    if (ws_size >= need) {
        f16*   emb16 = (f16*)d_ws;
        float* eTe   = (float*)((char*)d_ws + emb16_bytes);
        vq_prep<<<256, 256, 0, stream>>>(emb, emb16, eTe, loss_slot);
        vq_main<<<NROWS / BM, 256, 0, stream>>>(z, emb16, eTe, emb, out, loss_slot, loss_scale);
    } else {
        float* eTe = (ws_size >= K_CODES * sizeof(float)) ? (float*)d_ws : nullptr;
        vq_prep_fb<<<K_CODES / 4, 256, 0, stream>>>(emb, eTe, loss_slot);
        vq_main_fb<<<NROWS / 128, 128, 0, stream>>>(z, emb, eTe, out, loss_slot, loss_scale);
    }
}

// Round 4
// 117.004 us; speedup vs baseline: 2.5092x; 1.1817x over previous
//
#include <hip/hip_runtime.h>
#include <cstdint>

// VQ-VAE vector quantizer, MI355X (gfx950). Round 4.
// Evidence from round 3: vq_main 66us with MfmaUtil 9.3% ~ VALUBusy 11.2% ~
// Occupancy 9.9% -> latency-bound at 1 wave/SIMD (LDS 132 KB -> 1 block/CU,
// grid 256 -> 1 block/CU). Fix occupancy + chain ILP, keep verified math:
//  - BM=64, 4-wave blocks, grid 512 -> 2 blocks/CU co-resident (one computes
//    while the other drains its barrier). 8 waves/CU.
//  - slices of 64 codes, double-buffered 2x32 KB -> LDS ~66 KB (fits 2/CU).
//  - ct-pair unroll: 2 independent MFMA acc chains/wave x 2 waves/SIMD = 4
//    interleaved chains -> MFMA issue-bound, not dep-latency-bound.
//  - prep emits emb16 in fragment-slice-linear order -> staging async loads
//    are straight-line contiguous (no per-chunk address math in vq_main).

typedef _Float16 f16;
typedef f16 f16x8 __attribute__((ext_vector_type(8)));
typedef float f32x4 __attribute__((ext_vector_type(4)));

#define D_DIM 256
#define K_CODES 1024
#define NSPLIT 16
#define CSPLIT (K_CODES / NSPLIT)       // 64 codes per slice
#define SLICE_CH (CSPLIT * D_DIM / 8)   // 2048 16-byte chunks per slice
#define BM 64                           // rows per block (4 waves x 16 rows)

__device__ __forceinline__ void async_copy16(const void* g, void* l) {
    __builtin_amdgcn_global_load_lds(
        (const __attribute__((address_space(1))) void*)g,
        (__attribute__((address_space(3))) void*)l, 16, 0, 0);
}

// ---- Prep: zero loss slot; emb -> f16 (x1024) in fragment-slice-linear
// order; eTe = 1024*||e||^2. grid 256 x 256 threads.
// Chunk layout consumed by vq_main: slice sp (64 codes) holds 2048 chunks,
// chunk index ct*512 + s*64 + q*16 + m  <->  code (sp*64 + ct*16 + m),
// dims [s*32 + q*8, +8).
__global__ __launch_bounds__(256) void vq_prep(const float* __restrict__ emb,
                                               f16* __restrict__ emb16,
                                               float* __restrict__ eTe,
                                               float* __restrict__ loss_slot) {
    const int tid = threadIdx.x, wave = tid >> 6, lane = tid & 63;
    if (blockIdx.x == 0 && tid == 0) *loss_slot = 0.0f;

    if (tid < 128) {
        int ch   = blockIdx.x * 128 + tid;   // source chunk: code*32 + g
        int code = ch >> 5;
        int g    = ch & 31;                  // dim group of 8
        int sp = code >> 6, c = code & 63;
        int ct = c >> 4,    mm = c & 15;
        int s  = g >> 2,    qq = g & 3;
        int dst = sp * SLICE_CH + ct * 512 + s * 64 + qq * 16 + mm;
        const float* p = emb + (size_t)code * D_DIM + g * 8;
        float4 v0 = *(const float4*)p;
        float4 v1 = *(const float4*)(p + 4);
        f16x8 h = {(f16)(v0.x * 1024.f), (f16)(v0.y * 1024.f),
                   (f16)(v0.z * 1024.f), (f16)(v0.w * 1024.f),
                   (f16)(v1.x * 1024.f), (f16)(v1.y * 1024.f),
                   (f16)(v1.z * 1024.f), (f16)(v1.w * 1024.f)};
        *(f16x8*)(emb16 + (size_t)dst * 8) = h;
    }

    // eTe: one wave per code, 4 codes per block, pre-scaled by 1024.
    int code = blockIdx.x * 4 + wave;
    float4 v = ((const float4*)(emb + (size_t)code * D_DIM))[lane];
    float s = v.x * v.x + v.y * v.y + v.z * v.z + v.w * v.w;
    #pragma unroll
    for (int off = 32; off >= 1; off >>= 1) s += __shfl_down(s, off);
    if (lane == 0) eTe[code] = 1024.0f * s;
}

// ---- Main kernel -----------------------------------------------------------
__global__ __launch_bounds__(256, 2) void vq_main(const float* __restrict__ z,
                                                  const f16* __restrict__ emb16,
                                                  const float* __restrict__ eTe,
                                                  const float* __restrict__ emb,
                                                  float* __restrict__ out,
                                                  float* __restrict__ loss_slot,
                                                  float loss_scale) {
    __shared__ __align__(16) f16 sE[2][CSPLIT * D_DIM];   // 2 x 32 KB
    __shared__ int   s_idx[BM];
    __shared__ float s_red[4];

    const int tid  = threadIdx.x;
    const int wave = tid >> 6;        // 0..3
    const int lane = tid & 63;
    const int m    = lane & 15;       // A row / B col / C col
    const int q    = lane >> 4;       // 0..3: k-group / C row-group
    const size_t row0 = (size_t)blockIdx.x * BM + (size_t)wave * 16;

    // Stage slice 0 (async, straight-line contiguous: lane-linear 16 B).
    #pragma unroll
    for (int ii = 0; ii < SLICE_CH / 256; ii++) {
        int ch = ii * 256 + tid;
        async_copy16(emb16 + (size_t)ch * 8, sE[0] + (size_t)ch * 8);
    }

    // A fragments: 16 z rows per wave -> f16 registers (32 VGPRs).
    // Lane holds A[m][k = q*8 + j]; k-block s covers dims s*32..+31.
    f16x8 A[8];
    {
        const float* zr = z + (row0 + m) * D_DIM;
        #pragma unroll
        for (int s = 0; s < 8; s++) {
            const float* p = zr + s * 32 + q * 8;
            float4 v0 = *(const float4*)p;
            float4 v1 = *(const float4*)(p + 4);
            f16x8 a = {(f16)v0.x, (f16)v0.y, (f16)v0.z, (f16)v0.w,
                       (f16)v1.x, (f16)v1.y, (f16)v1.z, (f16)v1.w};
            A[s] = a;
        }
    }

    float best[4];
    int   bidx[4];
    #pragma unroll
    for (int r = 0; r < 4; r++) { best[r] = __builtin_inff(); bidx[r] = 0; }

    #pragma unroll 1
    for (int sp = 0; sp < NSPLIT; sp++) {
        // Drains this wave's async loads (compiler emits vmcnt(0) before
        // s_barrier) and syncs: sE[sp&1] staged, sE[(sp+1)&1] free.
        __syncthreads();

        if (sp + 1 < NSPLIT) {
            const f16* src = emb16 + (size_t)(sp + 1) * SLICE_CH * 8;
            f16* dst = sE[(sp + 1) & 1];
            #pragma unroll
            for (int ii = 0; ii < SLICE_CH / 256; ii++) {
                int ch = ii * 256 + tid;
                async_copy16(src + (size_t)ch * 8, dst + (size_t)ch * 8);
            }
        }

        const f16x8* B8 = (const f16x8*)sE[sp & 1];
        // 4 code-subtiles as 2 pairs: 2 independent acc chains in flight.
        #pragma unroll
        for (int cp = 0; cp < 2; cp++) {
            const int ct0 = cp * 2, ct1 = cp * 2 + 1;
            float ete0 = eTe[sp * CSPLIT + ct0 * 16 + m];
            float ete1 = eTe[sp * CSPLIT + ct1 * 16 + m];
            f32x4 a0 = {0.f, 0.f, 0.f, 0.f};
            f32x4 a1 = {0.f, 0.f, 0.f, 0.f};
            #pragma unroll
            for (int s = 0; s < 8; s++) {
                f16x8 b0 = B8[ct0 * 512 + s * 64 + lane];
                f16x8 b1 = B8[ct1 * 512 + s * 64 + lane];
                a0 = __builtin_amdgcn_mfma_f32_16x16x32_f16(A[s], b0, a0, 0, 0, 0);
                a1 = __builtin_amdgcn_mfma_f32_16x16x32_f16(A[s], b1, a1, 0, 0, 0);
            }
            int code0 = sp * CSPLIT + ct0 * 16 + m;
            int code1 = sp * CSPLIT + ct1 * 16 + m;
            #pragma unroll
            for (int r = 0; r < 4; r++) {
                float sc0 = fmaf(-2.0f, a0[r], ete0);
                if (sc0 < best[r]) { best[r] = sc0; bidx[r] = code0; }
                float sc1 = fmaf(-2.0f, a1[r], ete1);
                if (sc1 < best[r]) { best[r] = sc1; bidx[r] = code1; }
            }
        }
    }

    // Cross-lane argmin over the 16 column-lanes; first-index tie-break.
    #pragma unroll
    for (int r = 0; r < 4; r++) {
        float b  = best[r];
        int   bi = bidx[r];
        #pragma unroll
        for (int off = 8; off >= 1; off >>= 1) {
            float ob = __shfl_xor(b, off);
            int   oi = __shfl_xor(bi, off);
            if (ob < b || (ob == b && oi < bi)) { b = ob; bi = oi; }
        }
        if (m == 0) s_idx[wave * 16 + q * 4 + r] = bi;
    }
    __syncthreads();

    // Fused epilogue: out = emb[idx] (fp32, L2-hot); loss from in-register
    // f16 z fragments (z read from HBM exactly once).
    float lsum = 0.f;
    {
        int rl = wave * 16 + m;
        int idxv = s_idx[rl];
        const float* er = emb + (size_t)idxv * D_DIM;
        float* orow = out + ((size_t)blockIdx.x * BM + rl) * D_DIM;
        #pragma unroll
        for (int s = 0; s < 8; s++) {
            int dd = s * 32 + q * 8;
            float4 e0 = *(const float4*)(er + dd);
            float4 e1 = *(const float4*)(er + dd + 4);
            *(float4*)(orow + dd)     = e0;
            *(float4*)(orow + dd + 4) = e1;
            f16x8 a = A[s];
            float d0 = e0.x - (float)a[0], d1 = e0.y - (float)a[1];
            float d2 = e0.z - (float)a[2], d3 = e0.w - (float)a[3];
            float d4 = e1.x - (float)a[4], d5 = e1.y - (float)a[5];
            float d6 = e1.z - (float)a[6], d7 = e1.w - (float)a[7];
            lsum += d0*d0 + d1*d1 + d2*d2 + d3*d3 + d4*d4 + d5*d5 + d6*d6 + d7*d7;
        }
    }
    #pragma unroll
    for (int off = 32; off >= 1; off >>= 1) lsum += __shfl_down(lsum, off);
    if (lane == 0) s_red[wave] = lsum;
    __syncthreads();
    if (tid == 0)
        atomicAdd(loss_slot, (s_red[0] + s_red[1] + s_red[2] + s_red[3]) * loss_scale);
}

// ---- Fallback (round-2 structure, verified) — only if ws can't hold emb16.
__global__ __launch_bounds__(256) void vq_prep_fb(const float* __restrict__ emb,
                                                  float* __restrict__ eTe,
                                                  float* __restrict__ loss_slot) {
    if (blockIdx.x == 0 && threadIdx.x == 0) *loss_slot = 0.0f;
    if (!eTe) return;
    int gtid = blockIdx.x * 256 + threadIdx.x;
    int code = gtid >> 6;
    int lane = threadIdx.x & 63;
    if (code >= K_CODES) return;
    float4 v = ((const float4*)(emb + (size_t)code * D_DIM))[lane];
    float s = v.x * v.x + v.y * v.y + v.z * v.z + v.w * v.w;
    #pragma unroll
    for (int off = 32; off >= 1; off >>= 1) s += __shfl_down(s, off);
    if (lane == 0) eTe[code] = s;
}

__global__ __launch_bounds__(128) void vq_main_fb(const float* __restrict__ z,
                                                  const float* __restrict__ emb,
                                                  const float* __restrict__ eTe_g,
                                                  float* __restrict__ out,
                                                  float* __restrict__ loss_slot,
                                                  float loss_scale) {
    __shared__ __align__(16) f16 sE[128 * D_DIM];
    __shared__ float s_ete[128];
    __shared__ int   s_idx2[128];
    __shared__ float s_red2[2];

    const int tid  = threadIdx.x;
    const int wave = tid >> 6;
    const int lane = tid & 63;
    const int m    = lane & 15;
    const int q    = lane >> 4;
    const size_t row0 = (size_t)blockIdx.x * 128 + (size_t)wave * 64;

    f16x8 A[4][8];
    #pragma unroll
    for (int st = 0; st < 4; st++) {
        const float* zr = z + (row0 + st * 16 + m) * D_DIM;
        #pragma unroll
        for (int s = 0; s < 8; s++) {
            const float* p = zr + s * 32 + q * 8;
            float4 v0 = *(const float4*)p;
            float4 v1 = *(const float4*)(p + 4);
            f16x8 a = {(f16)v0.x, (f16)v0.y, (f16)v0.z, (f16)v0.w,
                       (f16)v1.x, (f16)v1.y, (f16)v1.z, (f16)v1.w};
            A[st][s] = a;
        }
    }
    float best[4][4]; int bidx[4][4];
    #pragma unroll
    for (int st = 0; st < 4; st++)
        #pragma unroll
        for (int r = 0; r < 4; r++) { best[st][r] = __builtin_inff(); bidx[st][r] = 0; }

    const f16x8* sE8 = (const f16x8*)sE;
    #pragma unroll 1
    for (int sp = 0; sp < 8; sp++) {
        __syncthreads();
        if (eTe_g) s_ete[tid] = 1024.0f * eTe_g[sp * 128 + tid];
        else {
            const float* p = emb + (size_t)(sp * 128 + tid) * D_DIM;
            float ss = 0.f;
            for (int j = 0; j < D_DIM / 4; j++) {
                float4 v = ((const float4*)p)[j];
                ss += v.x * v.x + v.y * v.y + v.z * v.z + v.w * v.w;
            }
            s_ete[tid] = 1024.0f * ss;
        }
        const float* ebase = emb + (size_t)sp * 128 * D_DIM;
        #pragma unroll 4
        for (int it = 0; it < 32; it++) {
            int ch = it * 128 + tid;
            int cc = ((ch >> 9) << 4) | (ch & 15);
            int g  = (ch >> 4) & 31;
            const float* p = ebase + cc * D_DIM + g * 8;
            float4 v0 = *(const float4*)p;
            float4 v1 = *(const float4*)(p + 4);
            f16x8 h = {(f16)(v0.x * 1024.f), (f16)(v0.y * 1024.f),
                       (f16)(v0.z * 1024.f), (f16)(v0.w * 1024.f),
                       (f16)(v1.x * 1024.f), (f16)(v1.y * 1024.f),
                       (f16)(v1.z * 1024.f), (f16)(v1.w * 1024.f)};
            *(f16x8*)(sE + (size_t)ch * 8) = h;
        }
        __syncthreads();
        for (int ct = 0; ct < 8; ct++) {
            f32x4 acc[4];
            #pragma unroll
            for (int st = 0; st < 4; st++) acc[st] = (f32x4){0.f, 0.f, 0.f, 0.f};
            #pragma unroll
            for (int s = 0; s < 8; s++) {
                f16x8 bh = sE8[ct * 512 + s * 64 + lane];
                #pragma unroll
                for (int st = 0; st < 4; st++)
                    acc[st] = __builtin_amdgcn_mfma_f32_16x16x32_f16(A[st][s], bh, acc[st], 0, 0, 0);
            }
            int codeL = ct * 16 + m;
            float ete = s_ete[codeL];
            int code  = sp * 128 + codeL;
            #pragma unroll
            for (int st = 0; st < 4; st++)
                #pragma unroll
                for (int r = 0; r < 4; r++) {
                    float sc = fmaf(-2.0f, acc[st][r], ete);
                    if (sc < best[st][r]) { best[st][r] = sc; bidx[st][r] = code; }
                }
        }
    }
    #pragma unroll
    for (int st = 0; st < 4; st++)
        #pragma unroll
        for (int r = 0; r < 4; r++) {
            float b = best[st][r]; int bi = bidx[st][r];
            #pragma unroll
            for (int off = 8; off >= 1; off >>= 1) {
                float ob = __shfl_xor(b, off);
                int   oi = __shfl_xor(bi, off);
                if (ob < b || (ob == b && oi < bi)) { b = ob; bi = oi; }
            }
            if (m == 0) s_idx2[wave * 64 + st * 16 + q * 4 + r] = bi;
        }
    __syncthreads();
    float lsum = 0.f;
    #pragma unroll
    for (int st = 0; st < 4; st++) {
        int rl = wave * 64 + st * 16 + m;
        int idxv = s_idx2[rl];
        const float* er = emb + (size_t)idxv * D_DIM;
        float* orow = out + ((size_t)blockIdx.x * 128 + rl) * D_DIM;
        #pragma unroll
        for (int s = 0; s < 8; s++) {
            int dd = s * 32 + q * 8;
            float4 e0 = *(const float4*)(er + dd);
            float4 e1 = *(const float4*)(er + dd + 4);
            *(float4*)(orow + dd)     = e0;
            *(float4*)(orow + dd + 4) = e1;
            f16x8 a = A[st][s];
            float d0 = e0.x - (float)a[0], d1 = e0.y - (float)a[1];
            float d2 = e0.z - (float)a[2], d3 = e0.w - (float)a[3];
            float d4 = e1.x - (float)a[4], d5 = e1.y - (float)a[5];
            float d6 = e1.z - (float)a[6], d7 = e1.w - (float)a[7];
            lsum += d0*d0 + d1*d1 + d2*d2 + d3*d3 + d4*d4 + d5*d5 + d6*d6 + d7*d7;
        }
    }
    #pragma unroll
    for (int off = 32; off >= 1; off >>= 1) lsum += __shfl_down(lsum, off);
    if (lane == 0) s_red2[wave] = lsum;
    __syncthreads();
    if (tid == 0) atomicAdd(loss_slot, (s_red2[0] + s_red2[1]) * loss_scale);
}

extern "C" void kernel_launch(void* const* d_in, const int* in_sizes, int n_in,
                              void* d_out, int out_size, void* d_ws, size_t ws_size,
                              hipStream_t stream) {
    const float* z   = (const float*)d_in[0];
    const float* emb = (const float*)d_in[1];
    float* out = (float*)d_out;
    const int NROWS = in_sizes[0] / D_DIM;              // 32768
    float* loss_slot = out + (size_t)in_sizes[0];
    float loss_scale = 1.25f / (float)in_sizes[0];

    const size_t emb16_bytes = (size_t)K_CODES * D_DIM * sizeof(f16);  // 512 KB
    const size_t need = emb16_bytes + K_CODES * sizeof(float);

    if (ws_size >= need) {
        f16*   emb16 = (f16*)d_ws;
        float* eTe   = (float*)((char*)d_ws + emb16_bytes);
        vq_prep<<<256, 256, 0, stream>>>(emb, emb16, eTe, loss_slot);
        vq_main<<<NROWS / BM, 256, 0, stream>>>(z, emb16, eTe, emb, out, loss_slot, loss_scale);
    } else {
        float* eTe = (ws_size >= K_CODES * sizeof(float)) ? (float*)d_ws : nullptr;
        vq_prep_fb<<<K_CODES / 4, 256, 0, stream>>>(emb, eTe, loss_slot);
        vq_main_fb<<<NROWS / 128, 128, 0, stream>>>(z, emb, eTe, out, loss_slot, loss_scale);
    }
}

// Round 5
// 116.195 us; speedup vs baseline: 2.5267x; 1.0070x over previous
//
#include <hip/hip_runtime.h>
#include <cstdint>

// VQ-VAE vector quantizer, MI355X (gfx950). Round 5.
// Evidence r4: 1 ds_read_b128 per MFMA -> LDS-pipe 20.5us vs MFMA 8.3us floor;
// measured 45us = 2.2x the ds floor (stall mult falls with waves/SIMD:
// r3 1/SIMD->6.5x, r4 2/SIMD->2.2x). Fix both with fp8:
//  - fp8 e4m3 scoring (emb x1024, z unscaled; dot err ~6e-4 only flips
//    near-ties; output err per flip <= 2*max|emb| = 1.95e-3 << 2.5e-2 thr).
//  - 16B LDS chunk = 2 k-steps -> 1 ds_read_b128 : 2 MFMAs; ds/CU 10.2us.
//  - 512-thr blocks: waves 0-3 score codes 0-511, waves 4-7 codes 512-1023
//    on the same 64 rows (2 independent dbuf streams, 64KB LDS), argmin
//    merged in LDS -> grid 512 x 8 waves = 16 waves/CU = 4/SIMD.
//  - loss = sum_rows(||z||^2_fp32 + best_score/1024): no z re-read.

typedef float f32x4 __attribute__((ext_vector_type(4)));
typedef long  l2    __attribute__((ext_vector_type(2)));
typedef _Float16 f16;
typedef f16 f16x8 __attribute__((ext_vector_type(8)));

#define D_DIM 256
#define K_CODES 1024
#define BM 64                       // rows per block
#define SLICE_CODES 64
#define SLICE_BYTES (SLICE_CODES * D_DIM)   // 16384 (fp8)
#define SLICE_CH (SLICE_BYTES / 16)         // 1024 chunks
#define NSLICE_G 8                  // slices per code-group (8 x 64 = 512 codes)

__device__ __forceinline__ void async_copy16(const void* g, void* l) {
    __builtin_amdgcn_global_load_lds(
        (const __attribute__((address_space(1))) void*)g,
        (__attribute__((address_space(3))) void*)l, 16, 0, 0);
}

__device__ __forceinline__ long pack_fp8x8(float x0, float x1, float x2, float x3,
                                           float x4, float x5, float x6, float x7) {
    int w0 = __builtin_amdgcn_cvt_pk_fp8_f32(x0, x1, 0, false);
    w0     = __builtin_amdgcn_cvt_pk_fp8_f32(x2, x3, w0, true);
    int w1 = __builtin_amdgcn_cvt_pk_fp8_f32(x4, x5, 0, false);
    w1     = __builtin_amdgcn_cvt_pk_fp8_f32(x6, x7, w1, true);
    int2 p = {w0, w1};
    return __builtin_bit_cast(long, p);
}

// ---- Prep: zero loss slot; emb -> fp8 (x1024) in fragment-slice-linear
// order (16 slices of 64 codes; chunk = ct*256 + t*64 + q*16 + m holds
// k-dims [t*64+q*8,+8) and [t*64+32+q*8,+8) of code sp*64+ct*16+m);
// eTe = 1024*||e||^2 fp32. grid 256 x 256.
__global__ __launch_bounds__(256) void vq_prep(const float* __restrict__ emb,
                                               char* __restrict__ emb8,
                                               float* __restrict__ eTe,
                                               float* __restrict__ loss_slot) {
    const int tid = threadIdx.x, wave = tid >> 6, lane = tid & 63;
    if (blockIdx.x == 0 && tid == 0) *loss_slot = 0.0f;

    if (blockIdx.x < 64) {
        int ch  = blockIdx.x * 256 + tid;     // 16384 chunks
        int sp  = ch >> 10;
        int rem = ch & 1023;
        int ct  = rem >> 8;
        int t   = (rem >> 6) & 3;
        int l   = rem & 63;
        int qq  = l >> 4, mm = l & 15;
        int code = sp * 64 + ct * 16 + mm;
        const float* p = emb + (size_t)code * D_DIM;
        int b0 = t * 64 + qq * 8;
        int b1 = b0 + 32;
        float4 v0 = *(const float4*)(p + b0);
        float4 v1 = *(const float4*)(p + b0 + 4);
        float4 v2 = *(const float4*)(p + b1);
        float4 v3 = *(const float4*)(p + b1 + 4);
        l2 out;
        out.x = pack_fp8x8(v0.x * 1024.f, v0.y * 1024.f, v0.z * 1024.f, v0.w * 1024.f,
                           v1.x * 1024.f, v1.y * 1024.f, v1.z * 1024.f, v1.w * 1024.f);
        out.y = pack_fp8x8(v2.x * 1024.f, v2.y * 1024.f, v2.z * 1024.f, v2.w * 1024.f,
                           v3.x * 1024.f, v3.y * 1024.f, v3.z * 1024.f, v3.w * 1024.f);
        *(l2*)(emb8 + (size_t)ch * 16) = out;
    }

    // eTe: one wave per code, 4 codes per block, pre-scaled by 1024.
    int code = blockIdx.x * 4 + wave;
    float4 v = ((const float4*)(emb + (size_t)code * D_DIM))[lane];
    float s = v.x * v.x + v.y * v.y + v.z * v.z + v.w * v.w;
    #pragma unroll
    for (int off = 32; off >= 1; off >>= 1) s += __shfl_down(s, off);
    if (lane == 0) eTe[code] = 1024.0f * s;
}

// ---- Main kernel -----------------------------------------------------------
__global__ __launch_bounds__(512, 4) void vq_main(const float* __restrict__ z,
                                                  const char* __restrict__ emb8,
                                                  const float* __restrict__ eTe,
                                                  const float* __restrict__ emb,
                                                  float* __restrict__ out,
                                                  float* __restrict__ loss_slot,
                                                  float loss_scale) {
    __shared__ __align__(16) char sB[2][2][SLICE_BYTES];   // [group][dbuf] 64 KB
    __shared__ float s_best[2][BM];
    __shared__ int   s_bidx[2][BM];
    __shared__ int   s_idx[BM];
    __shared__ float s_fin[BM];
    __shared__ float s_red[4];

    const int tid  = threadIdx.x;
    const int wave = tid >> 6;        // 0..7
    const int g    = tid >> 8;        // code-group 0/1
    const int wl   = wave & 3;        // wave within group -> row strip
    const int lane = tid & 63;
    const int m    = lane & 15;       // A row / B col (code) / C col
    const int q    = lane >> 4;       // k-group / C row-group
    const int tidl = tid & 255;       // thread within group

    // Stage this group's slice 0 (async) before the A load.
    {
        const char* src = emb8 + (size_t)(g * NSLICE_G) * SLICE_BYTES;
        char* dst = sB[g][0];
        #pragma unroll
        for (int ii = 0; ii < 4; ii++) {
            int ch = ii * 256 + tidl;
            async_copy16(src + (size_t)ch * 16, dst + (size_t)ch * 16);
        }
    }

    // A fragments: 16 z rows per wave -> fp8 (16 VGPRs) + per-lane sum(z^2).
    // Lane holds A[m][k = q*8 + j]; k-block s covers dims s*32..+31.
    long A8[8];
    float zsq = 0.f;
    {
        const float* zr = z + ((size_t)blockIdx.x * BM + wl * 16 + m) * D_DIM;
        #pragma unroll
        for (int s = 0; s < 8; s++) {
            const float* p = zr + s * 32 + q * 8;
            float4 v0 = *(const float4*)p;
            float4 v1 = *(const float4*)(p + 4);
            zsq += v0.x * v0.x + v0.y * v0.y + v0.z * v0.z + v0.w * v0.w
                 + v1.x * v1.x + v1.y * v1.y + v1.z * v1.z + v1.w * v1.w;
            A8[s] = pack_fp8x8(v0.x, v0.y, v0.z, v0.w, v1.x, v1.y, v1.z, v1.w);
        }
    }

    float best[4];
    int   bidx[4];
    #pragma unroll
    for (int r = 0; r < 4; r++) { best[r] = __builtin_inff(); bidx[r] = 0; }

    #pragma unroll 1
    for (int i = 0; i < NSLICE_G; i++) {
        // Barrier drains this wave's async loads (compiler emits vmcnt(0)
        // before s_barrier): sB[g][i&1] staged; sB[g][(i+1)&1] free.
        __syncthreads();

        if (i + 1 < NSLICE_G) {
            const char* src = emb8 + (size_t)(g * NSLICE_G + i + 1) * SLICE_BYTES;
            char* dst = sB[g][(i + 1) & 1];
            #pragma unroll
            for (int ii = 0; ii < 4; ii++) {
                int ch = ii * 256 + tidl;
                async_copy16(src + (size_t)ch * 16, dst + (size_t)ch * 16);
            }
        }

        const char* B = sB[g][i & 1];
        const int cbase = g * 512 + i * SLICE_CODES;
        float ete[4];
        #pragma unroll
        for (int ct = 0; ct < 4; ct++) ete[ct] = eTe[cbase + ct * 16 + m];

        f32x4 acc[4];
        #pragma unroll
        for (int ct = 0; ct < 4; ct++) acc[ct] = (f32x4){0.f, 0.f, 0.f, 0.f};

        // 4 s-pair steps: per step 4 ds_read_b128 (one per ct) feed 8 MFMAs;
        // 4 independent chains/wave x 4 waves/SIMD.
        #pragma unroll
        for (int t = 0; t < 4; t++) {
            l2 c0 = *(const l2*)(B + (size_t)((0 * 256) + t * 64 + lane) * 16);
            l2 c1 = *(const l2*)(B + (size_t)((1 * 256) + t * 64 + lane) * 16);
            l2 c2 = *(const l2*)(B + (size_t)((2 * 256) + t * 64 + lane) * 16);
            l2 c3 = *(const l2*)(B + (size_t)((3 * 256) + t * 64 + lane) * 16);
            acc[0] = __builtin_amdgcn_mfma_f32_16x16x32_fp8_fp8(A8[2*t],   c0.x, acc[0], 0, 0, 0);
            acc[1] = __builtin_amdgcn_mfma_f32_16x16x32_fp8_fp8(A8[2*t],   c1.x, acc[1], 0, 0, 0);
            acc[2] = __builtin_amdgcn_mfma_f32_16x16x32_fp8_fp8(A8[2*t],   c2.x, acc[2], 0, 0, 0);
            acc[3] = __builtin_amdgcn_mfma_f32_16x16x32_fp8_fp8(A8[2*t],   c3.x, acc[3], 0, 0, 0);
            acc[0] = __builtin_amdgcn_mfma_f32_16x16x32_fp8_fp8(A8[2*t+1], c0.y, acc[0], 0, 0, 0);
            acc[1] = __builtin_amdgcn_mfma_f32_16x16x32_fp8_fp8(A8[2*t+1], c1.y, acc[1], 0, 0, 0);
            acc[2] = __builtin_amdgcn_mfma_f32_16x16x32_fp8_fp8(A8[2*t+1], c2.y, acc[2], 0, 0, 0);
            acc[3] = __builtin_amdgcn_mfma_f32_16x16x32_fp8_fp8(A8[2*t+1], c3.y, acc[3], 0, 0, 0);
        }

        #pragma unroll
        for (int ct = 0; ct < 4; ct++) {
            int code = cbase + ct * 16 + m;
            #pragma unroll
            for (int r = 0; r < 4; r++) {
                float sc = fmaf(-2.0f, acc[ct][r], ete[ct]);
                if (sc < best[r]) { best[r] = sc; bidx[r] = code; }
            }
        }
    }

    // Cross-lane argmin over the 16 column-lanes; first-index tie-break.
    #pragma unroll
    for (int r = 0; r < 4; r++) {
        float b  = best[r];
        int   bi = bidx[r];
        #pragma unroll
        for (int off = 8; off >= 1; off >>= 1) {
            float ob = __shfl_xor(b, off);
            int   oi = __shfl_xor(bi, off);
            if (ob < b || (ob == b && oi < bi)) { b = ob; bi = oi; }
        }
        if (m == 0) {
            s_best[g][wl * 16 + q * 4 + r] = b;
            s_bidx[g][wl * 16 + q * 4 + r] = bi;
        }
    }
    __syncthreads();

    // Merge the two code-groups (group-0 indices < group-1: tie -> group 0).
    if (tid < BM) {
        float b0 = s_best[0][tid], b1 = s_best[1][tid];
        int   i0 = s_bidx[0][tid], i1 = s_bidx[1][tid];
        bool take1 = (b1 < b0);
        s_idx[tid] = take1 ? i1 : i0;
        s_fin[tid] = take1 ? b1 : b0;
    }
    __syncthreads();

    // Fused epilogue (group 0 only): out = emb[idx] (fp32, L2-hot);
    // loss_row = sum(z^2) + best_score/1024.
    float lsum = 0.f;
    if (g == 0) {
        int rl = wl * 16 + m;
        int idxv = s_idx[rl];
        const float* er = emb + (size_t)idxv * D_DIM;
        float* orow = out + ((size_t)blockIdx.x * BM + rl) * D_DIM;
        #pragma unroll
        for (int s = 0; s < 8; s++) {
            int dd = s * 32 + q * 8;
            *(float4*)(orow + dd)     = *(const float4*)(er + dd);
            *(float4*)(orow + dd + 4) = *(const float4*)(er + dd + 4);
        }
        float zrow = zsq + __shfl_xor(zsq, 16);
        zrow += __shfl_xor(zrow, 32);
        if (q == 0) lsum = zrow + s_fin[rl] * (1.0f / 1024.0f);
        #pragma unroll
        for (int off = 32; off >= 1; off >>= 1) lsum += __shfl_down(lsum, off);
        if (lane == 0) s_red[wl] = lsum;
    }
    __syncthreads();
    if (tid == 0)
        atomicAdd(loss_slot, (s_red[0] + s_red[1] + s_red[2] + s_red[3]) * loss_scale);
}

// ---- Fallback (round-2 structure, verified) — only if ws too small. --------
__global__ __launch_bounds__(256) void vq_prep_fb(const float* __restrict__ emb,
                                                  float* __restrict__ eTe,
                                                  float* __restrict__ loss_slot) {
    if (blockIdx.x == 0 && threadIdx.x == 0) *loss_slot = 0.0f;
    if (!eTe) return;
    int gtid = blockIdx.x * 256 + threadIdx.x;
    int code = gtid >> 6;
    int lane = threadIdx.x & 63;
    if (code >= K_CODES) return;
    float4 v = ((const float4*)(emb + (size_t)code * D_DIM))[lane];
    float s = v.x * v.x + v.y * v.y + v.z * v.z + v.w * v.w;
    #pragma unroll
    for (int off = 32; off >= 1; off >>= 1) s += __shfl_down(s, off);
    if (lane == 0) eTe[code] = s;
}

__global__ __launch_bounds__(128) void vq_main_fb(const float* __restrict__ z,
                                                  const float* __restrict__ emb,
                                                  const float* __restrict__ eTe_g,
                                                  float* __restrict__ out,
                                                  float* __restrict__ loss_slot,
                                                  float loss_scale) {
    __shared__ __align__(16) f16 sE[128 * D_DIM];
    __shared__ float s_ete[128];
    __shared__ int   s_idx2[128];
    __shared__ float s_red2[2];

    const int tid  = threadIdx.x;
    const int wave = tid >> 6;
    const int lane = tid & 63;
    const int m    = lane & 15;
    const int q    = lane >> 4;
    const size_t row0 = (size_t)blockIdx.x * 128 + (size_t)wave * 64;

    f16x8 A[4][8];
    #pragma unroll
    for (int st = 0; st < 4; st++) {
        const float* zr = z + (row0 + st * 16 + m) * D_DIM;
        #pragma unroll
        for (int s = 0; s < 8; s++) {
            const float* p = zr + s * 32 + q * 8;
            float4 v0 = *(const float4*)p;
            float4 v1 = *(const float4*)(p + 4);
            f16x8 a = {(f16)v0.x, (f16)v0.y, (f16)v0.z, (f16)v0.w,
                       (f16)v1.x, (f16)v1.y, (f16)v1.z, (f16)v1.w};
            A[st][s] = a;
        }
    }
    float best[4][4]; int bidx[4][4];
    #pragma unroll
    for (int st = 0; st < 4; st++)
        #pragma unroll
        for (int r = 0; r < 4; r++) { best[st][r] = __builtin_inff(); bidx[st][r] = 0; }

    const f16x8* sE8 = (const f16x8*)sE;
    #pragma unroll 1
    for (int sp = 0; sp < 8; sp++) {
        __syncthreads();
        if (eTe_g) s_ete[tid] = 1024.0f * eTe_g[sp * 128 + tid];
        else {
            const float* p = emb + (size_t)(sp * 128 + tid) * D_DIM;
            float ss = 0.f;
            for (int j = 0; j < D_DIM / 4; j++) {
                float4 v = ((const float4*)p)[j];
                ss += v.x * v.x + v.y * v.y + v.z * v.z + v.w * v.w;
            }
            s_ete[tid] = 1024.0f * ss;
        }
        const float* ebase = emb + (size_t)sp * 128 * D_DIM;
        #pragma unroll 4
        for (int it = 0; it < 32; it++) {
            int ch = it * 128 + tid;
            int cc = ((ch >> 9) << 4) | (ch & 15);
            int gg = (ch >> 4) & 31;
            const float* p = ebase + cc * D_DIM + gg * 8;
            float4 v0 = *(const float4*)p;
            float4 v1 = *(const float4*)(p + 4);
            f16x8 h = {(f16)(v0.x * 1024.f), (f16)(v0.y * 1024.f),
                       (f16)(v0.z * 1024.f), (f16)(v0.w * 1024.f),
                       (f16)(v1.x * 1024.f), (f16)(v1.y * 1024.f),
                       (f16)(v1.z * 1024.f), (f16)(v1.w * 1024.f)};
            *(f16x8*)(sE + (size_t)ch * 8) = h;
        }
        __syncthreads();
        for (int ct = 0; ct < 8; ct++) {
            f32x4 acc[4];
            #pragma unroll
            for (int st = 0; st < 4; st++) acc[st] = (f32x4){0.f, 0.f, 0.f, 0.f};
            #pragma unroll
            for (int s = 0; s < 8; s++) {
                f16x8 bh = sE8[ct * 512 + s * 64 + lane];
                #pragma unroll
                for (int st = 0; st < 4; st++)
                    acc[st] = __builtin_amdgcn_mfma_f32_16x16x32_f16(A[st][s], bh, acc[st], 0, 0, 0);
            }
            int codeL = ct * 16 + m;
            float ete = s_ete[codeL];
            int code  = sp * 128 + codeL;
            #pragma unroll
            for (int st = 0; st < 4; st++)
                #pragma unroll
                for (int r = 0; r < 4; r++) {
                    float sc = fmaf(-2.0f, acc[st][r], ete);
                    if (sc < best[st][r]) { best[st][r] = sc; bidx[st][r] = code; }
                }
        }
    }
    #pragma unroll
    for (int st = 0; st < 4; st++)
        #pragma unroll
        for (int r = 0; r < 4; r++) {
            float b = best[st][r]; int bi = bidx[st][r];
            #pragma unroll
            for (int off = 8; off >= 1; off >>= 1) {
                float ob = __shfl_xor(b, off);
                int   oi = __shfl_xor(bi, off);
                if (ob < b || (ob == b && oi < bi)) { b = ob; bi = oi; }
            }
            if (m == 0) s_idx2[wave * 64 + st * 16 + q * 4 + r] = bi;
        }
    __syncthreads();
    float lsum = 0.f;
    #pragma unroll
    for (int st = 0; st < 4; st++) {
        int rl = wave * 64 + st * 16 + m;
        int idxv = s_idx2[rl];
        const float* er = emb + (size_t)idxv * D_DIM;
        float* orow = out + ((size_t)blockIdx.x * 128 + rl) * D_DIM;
        #pragma unroll
        for (int s = 0; s < 8; s++) {
            int dd = s * 32 + q * 8;
            float4 e0 = *(const float4*)(er + dd);
            float4 e1 = *(const float4*)(er + dd + 4);
            *(float4*)(orow + dd)     = e0;
            *(float4*)(orow + dd + 4) = e1;
            f16x8 a = A[st][s];
            float d0 = e0.x - (float)a[0], d1 = e0.y - (float)a[1];
            float d2 = e0.z - (float)a[2], d3 = e0.w - (float)a[3];
            float d4 = e1.x - (float)a[4], d5 = e1.y - (float)a[5];
            float d6 = e1.z - (float)a[6], d7 = e1.w - (float)a[7];
            lsum += d0*d0 + d1*d1 + d2*d2 + d3*d3 + d4*d4 + d5*d5 + d6*d6 + d7*d7;
        }
    }
    #pragma unroll
    for (int off = 32; off >= 1; off >>= 1) lsum += __shfl_down(lsum, off);
    if (lane == 0) s_red2[wave] = lsum;
    __syncthreads();
    if (tid == 0) atomicAdd(loss_slot, (s_red2[0] + s_red2[1]) * loss_scale);
}

extern "C" void kernel_launch(void* const* d_in, const int* in_sizes, int n_in,
                              void* d_out, int out_size, void* d_ws, size_t ws_size,
                              hipStream_t stream) {
    const float* z   = (const float*)d_in[0];
    const float* emb = (const float*)d_in[1];
    float* out = (float*)d_out;
    const int NROWS = in_sizes[0] / D_DIM;              // 32768
    float* loss_slot = out + (size_t)in_sizes[0];
    float loss_scale = 1.25f / (float)in_sizes[0];

    const size_t emb8_bytes = (size_t)K_CODES * D_DIM;  // 256 KB
    const size_t need = emb8_bytes + K_CODES * sizeof(float);

    if (ws_size >= need) {
        char*  emb8 = (char*)d_ws;
        float* eTe  = (float*)((char*)d_ws + emb8_bytes);
        vq_prep<<<256, 256, 0, stream>>>(emb, emb8, eTe, loss_slot);
        vq_main<<<NROWS / BM, 512, 0, stream>>>(z, emb8, eTe, emb, out, loss_slot, loss_scale);
    } else {
        float* eTe = (ws_size >= K_CODES * sizeof(float)) ? (float*)d_ws : nullptr;
        vq_prep_fb<<<K_CODES / 4, 256, 0, stream>>>(emb, eTe, loss_slot);
        vq_main_fb<<<NROWS / 128, 128, 0, stream>>>(z, emb, eTe, out, loss_slot, loss_scale);
    }
}